// Round 1
// baseline (258.795 us; speedup 1.0000x reference)
//
#include <hip/hip_runtime.h>
#include <math.h>

#define C_CLASSES 32000
#define C4 (C_CLASSES / 4)          // 8000 float4 per row
#define BLOCK 1024
#define NWAVES (BLOCK / 64)         // 16
#define ACT_CAP 2048                // active-set buffer capacity (expected ~17)

__global__ __launch_bounds__(BLOCK, 1) void sparsemax_row_kernel(
    const float* __restrict__ input,
    const float* __restrict__ target,
    const float* __restrict__ weight,
    float* __restrict__ rowloss)
{
    __shared__ float4 s_row[C4];        // 128000 B: raw input row
    __shared__ float  s_act[ACT_CAP];   // 8192 B: active z values (z > -1)
    __shared__ float  s_red[NWAVES];
    __shared__ float  s_redk[NWAVES];
    __shared__ float  s_bcast;
    __shared__ int    s_cnt;
    __shared__ int    s_flag;

    const int row  = blockIdx.x;
    const int tid  = threadIdx.x;
    const int lane = tid & 63;
    const int wid  = tid >> 6;

    const float4* in4 = (const float4*)(input + (size_t)row * C_CLASSES);

    // ---- Phase 1: stage row into LDS, compute row max ----
    float mx = -3.4e38f;
    for (int i = tid; i < C4; i += BLOCK) {
        float4 v = in4[i];
        s_row[i] = v;
        mx = fmaxf(mx, fmaxf(fmaxf(v.x, v.y), fmaxf(v.z, v.w)));
    }
    #pragma unroll
    for (int m = 32; m >= 1; m >>= 1) mx = fmaxf(mx, __shfl_xor(mx, m, 64));
    if (lane == 0) s_red[wid] = mx;
    if (tid == 0) { s_cnt = 0; s_flag = 0; }
    __syncthreads();
    if (tid < 64) {
        float x = (lane < NWAVES) ? s_red[lane] : -3.4e38f;
        #pragma unroll
        for (int m = 32; m >= 1; m >>= 1) x = fmaxf(x, __shfl_xor(x, m, 64));
        if (lane == 0) s_bcast = x;
    }
    __syncthreads();
    const float rowmax = s_bcast;

    // ---- Phase 2: collect active set {z > -1} (tau* is in [-1, 0)) ----
    const float* s_f = (const float*)s_row;
    for (int i = tid; i < C_CLASSES; i += BLOCK) {
        float z = s_f[i] - rowmax;
        if (z > -1.0f) {
            int p = atomicAdd(&s_cnt, 1);
            if (p < ACT_CAP) s_act[p] = z;
        }
    }
    __syncthreads();
    const int cnt = s_cnt;
    float tau;

    if (cnt <= ACT_CAP) {
        // Newton / Michelot on the small active set, wave 0 only.
        if (wid == 0) {
            float t = -1.0f;
            for (int it = 0; it < 100; ++it) {
                float s = 0.0f, k = 0.0f;
                for (int i = lane; i < cnt; i += 64) {
                    float z = s_act[i];
                    if (z > t) { s += z; k += 1.0f; }
                }
                #pragma unroll
                for (int m = 32; m >= 1; m >>= 1) {
                    s += __shfl_xor(s, m, 64);
                    k += __shfl_xor(k, m, 64);
                }
                float tn = (s - 1.0f) / k;   // k >= 1: z_max = 0 > t always
                if (!(tn > t)) break;        // converged (monotone from below)
                t = tn;
            }
            if (lane == 0) s_bcast = t;
        }
        __syncthreads();
        tau = s_bcast;
    } else {
        // Fallback: block-wide Newton over the full LDS row.
        float t = -1.0f;
        for (int it = 0; it < 64; ++it) {
            float s = 0.0f, k = 0.0f;
            for (int i = tid; i < C_CLASSES; i += BLOCK) {
                float z = s_f[i] - rowmax;
                if (z > t) { s += z; k += 1.0f; }
            }
            #pragma unroll
            for (int m = 32; m >= 1; m >>= 1) {
                s += __shfl_xor(s, m, 64);
                k += __shfl_xor(k, m, 64);
            }
            if (lane == 0) { s_red[wid] = s; s_redk[wid] = k; }
            __syncthreads();
            if (tid == 0) {
                float S = 0.0f, K = 0.0f;
                for (int w = 0; w < NWAVES; ++w) { S += s_red[w]; K += s_redk[w]; }
                float tn = (S - 1.0f) / K;
                if (!(tn > t)) s_flag = 1;
                else           s_bcast = tn;
            }
            __syncthreads();
            if (s_flag) break;
            t = s_bcast;
            __syncthreads();
        }
        tau = t;
    }
    __syncthreads();

    // ---- Phase 3: stream target + weight, fused loss, block sum ----
    const float4* tg4 = (const float4*)(target + (size_t)row * C_CLASSES);
    const float4* w4  = (const float4*)weight;
    const float tau2 = tau * tau;
    float acc = 0.0f;
    for (int i = tid; i < C4; i += BLOCK) {
        float4 t4 = tg4[i];
        float4 wv = w4[i];
        float4 zv = s_row[i];
        {
            float z = zv.x - rowmax, t = t4.x;
            acc += wv.x * (0.5f * (fmaxf(0.0f, z*z - tau2) + t*t) - t*z);
        }
        {
            float z = zv.y - rowmax, t = t4.y;
            acc += wv.y * (0.5f * (fmaxf(0.0f, z*z - tau2) + t*t) - t*z);
        }
        {
            float z = zv.z - rowmax, t = t4.z;
            acc += wv.z * (0.5f * (fmaxf(0.0f, z*z - tau2) + t*t) - t*z);
        }
        {
            float z = zv.w - rowmax, t = t4.w;
            acc += wv.w * (0.5f * (fmaxf(0.0f, z*z - tau2) + t*t) - t*z);
        }
    }
    #pragma unroll
    for (int m = 32; m >= 1; m >>= 1) acc += __shfl_xor(acc, m, 64);
    if (lane == 0) s_red[wid] = acc;
    __syncthreads();
    if (tid < 64) {
        float x = (lane < NWAVES) ? s_red[lane] : 0.0f;
        #pragma unroll
        for (int m = 32; m >= 1; m >>= 1) x += __shfl_xor(x, m, 64);
        if (lane == 0) rowloss[row] = x;
    }
}

__global__ __launch_bounds__(1024) void reduce_mean_kernel(
    const float* __restrict__ rowloss, float* __restrict__ out, int B)
{
    __shared__ float s_red[16];
    const int tid  = threadIdx.x;
    const int lane = tid & 63;
    const int wid  = tid >> 6;
    float acc = 0.0f;
    for (int i = tid; i < B; i += 1024) acc += rowloss[i];
    #pragma unroll
    for (int m = 32; m >= 1; m >>= 1) acc += __shfl_xor(acc, m, 64);
    if (lane == 0) s_red[wid] = acc;
    __syncthreads();
    if (tid < 64) {
        float x = (lane < 16) ? s_red[lane] : 0.0f;
        #pragma unroll
        for (int m = 32; m >= 1; m >>= 1) x += __shfl_xor(x, m, 64);
        if (lane == 0) out[0] = x / (float)B;
    }
}

extern "C" void kernel_launch(void* const* d_in, const int* in_sizes, int n_in,
                              void* d_out, int out_size, void* d_ws, size_t ws_size,
                              hipStream_t stream)
{
    const float* input  = (const float*)d_in[0];
    const float* target = (const float*)d_in[1];
    const float* weight = (const float*)d_in[2];
    float* out     = (float*)d_out;
    float* rowloss = (float*)d_ws;

    const int C = in_sizes[2];           // 32000
    const int B = in_sizes[0] / C;       // 4096

    sparsemax_row_kernel<<<B, BLOCK, 0, stream>>>(input, target, weight, rowloss);
    reduce_mean_kernel<<<1, 1024, 0, stream>>>(rowloss, out, B);
}